// Round 1
// baseline (1962.015 us; speedup 1.0000x reference)
//
#include <hip/hip_runtime.h>

#define NP 200000
#define NU 100000
#define NBR 5000
#define NCAT 2000
#define NSH 1000
#define NN (NP + NU + NBR + NCAT + NSH) /* 308000 */
#define OFF_U NP
#define OFF_B (NP + NU)
#define OFF_C (NP + NU + NBR)
#define OFF_S (NP + NU + NBR + NCAT)

// ---------------------------------------------------------------------------
// Projection: x[0..NP) rows = relu(product_x @ proj_W + proj_b)
// 64-lane group handles 8 rows; W reads coalesced, x-row reads wave-uniform.
// ---------------------------------------------------------------------------
__global__ __launch_bounds__(256) void proj_kernel(
    const float* __restrict__ px, const float* __restrict__ W,
    const float* __restrict__ bias, float* __restrict__ x) {
  const int lane = threadIdx.x & 63;
  const int grp = blockIdx.x * 4 + (threadIdx.x >> 6);
  const int nGrp = gridDim.x * 4;
  const float bv = bias[lane];
  for (int rowBase = grp * 8; rowBase < NP; rowBase += nGrp * 8) {
    float acc[8];
#pragma unroll
    for (int r = 0; r < 8; ++r) acc[r] = bv;
    for (int k4 = 0; k4 < 96; ++k4) {
      const float w0 = W[(4 * k4 + 0) * 64 + lane];
      const float w1 = W[(4 * k4 + 1) * 64 + lane];
      const float w2 = W[(4 * k4 + 2) * 64 + lane];
      const float w3 = W[(4 * k4 + 3) * 64 + lane];
#pragma unroll
      for (int r = 0; r < 8; ++r) {
        const float4 xv =
            *reinterpret_cast<const float4*>(px + (size_t)(rowBase + r) * 384 + 4 * k4);
        acc[r] = fmaf(xv.x, w0, acc[r]);
        acc[r] = fmaf(xv.y, w1, acc[r]);
        acc[r] = fmaf(xv.z, w2, acc[r]);
        acc[r] = fmaf(xv.w, w3, acc[r]);
      }
    }
#pragma unroll
    for (int r = 0; r < 8; ++r)
      x[(size_t)(rowBase + r) * 64 + lane] = fmaxf(acc[r], 0.f);
  }
}

// ---------------------------------------------------------------------------
// Degree count over one relation (both directions; int atomics).
// ---------------------------------------------------------------------------
__global__ void degree_kernel(const int* __restrict__ src, const int* __restrict__ dst,
                              int n, int offS, int offD, int* __restrict__ cnt) {
  int e = blockIdx.x * 256 + threadIdx.x;
  if (e >= n) return;
  atomicAdd(&cnt[src[e] + offS], 1);
  atomicAdd(&cnt[dst[e] + offD], 1);
}

// ---------------------------------------------------------------------------
// 3-kernel exclusive scan over cnt[NN] -> rowptr[NN+1]
// ---------------------------------------------------------------------------
__global__ __launch_bounds__(256) void scan1_kernel(const int* __restrict__ cnt,
                                                    int* __restrict__ blockSums, int n) {
  __shared__ int sdata[256];
  const int base = blockIdx.x * 1024;
  int s = 0;
  for (int i = threadIdx.x; i < 1024; i += 256) {
    int idx = base + i;
    if (idx < n) s += cnt[idx];
  }
  sdata[threadIdx.x] = s;
  __syncthreads();
  for (int off = 128; off > 0; off >>= 1) {
    if (threadIdx.x < off) sdata[threadIdx.x] += sdata[threadIdx.x + off];
    __syncthreads();
  }
  if (threadIdx.x == 0) blockSums[blockIdx.x] = sdata[0];
}

__global__ __launch_bounds__(512) void scan2_kernel(int* __restrict__ blockSums, int nb) {
  __shared__ int sd[512];
  const int t = threadIdx.x;
  const int v = (t < nb) ? blockSums[t] : 0;
  sd[t] = v;
  __syncthreads();
  for (int off = 1; off < 512; off <<= 1) {
    int add = (t >= off) ? sd[t - off] : 0;
    __syncthreads();
    sd[t] += add;
    __syncthreads();
  }
  if (t < nb) blockSums[t] = sd[t] - v;  // exclusive
}

__global__ __launch_bounds__(256) void scan3_kernel(const int* __restrict__ cnt,
                                                    const int* __restrict__ blockSums,
                                                    int* __restrict__ rowptr, int n) {
  __shared__ int wsum[4];
  const int base = blockIdx.x * 1024;
  const int t = threadIdx.x, lane = t & 63, wid = t >> 6;
  const int idx0 = base + t * 4;
  int v[4];
#pragma unroll
  for (int j = 0; j < 4; ++j) {
    int idx = idx0 + j;
    v[j] = (idx < n) ? cnt[idx] : 0;
  }
  const int s = v[0] + v[1] + v[2] + v[3];
  int incl = s;
  for (int off = 1; off < 64; off <<= 1) {
    int tt = __shfl_up(incl, off);
    if (lane >= off) incl += tt;
  }
  if (lane == 63) wsum[wid] = incl;
  __syncthreads();
  int wOff = 0;
#pragma unroll
  for (int w = 0; w < 4; ++w)
    if (w < wid) wOff += wsum[w];
  int run = blockSums[blockIdx.x] + wOff + (incl - s);
#pragma unroll
  for (int j = 0; j < 4; ++j) {
    int idx = idx0 + j;
    if (idx < n) {
      rowptr[idx] = run;
      run += v[j];
      if (idx == n - 1) rowptr[n] = run;
    }
  }
}

// ---------------------------------------------------------------------------
// Bucket-scatter in-neighbor lists (CSR adjacency), int atomics on cursor.
// ---------------------------------------------------------------------------
__global__ void fill_kernel(const int* __restrict__ src, const int* __restrict__ dst,
                            int n, int offS, int offD, const int* __restrict__ rowptr,
                            int* __restrict__ cursor, int* __restrict__ eidx) {
  int e = blockIdx.x * 256 + threadIdx.x;
  if (e >= n) return;
  const int a = src[e] + offS;
  const int b = dst[e] + offD;
  int pa = atomicAdd(&cursor[a], 1);
  eidx[rowptr[a] + pa] = b;  // b is an in-neighbor of a
  int pb = atomicAdd(&cursor[b], 1);
  eidx[rowptr[b] + pb] = a;  // a is an in-neighbor of b
}

// ---------------------------------------------------------------------------
// Fused mean-aggregate + SAGE linear:
//   out = act( (mean_{j in N(i)} xin_j) @ Wl + bl + xin_i @ Wr )
// One wave per node. W columns live in VGPRs (full static unroll).
// ---------------------------------------------------------------------------
template <int DOUT, bool RELU>
__global__ __launch_bounds__(256) void agg_fin_kernel(
    const int* __restrict__ rowptr, const int* __restrict__ eidx,
    const float* __restrict__ xin, const float* __restrict__ Wl,
    const float* __restrict__ bl, const float* __restrict__ Wr,
    float* __restrict__ out) {
  const int lane = threadIdx.x & 63;
  const int wid = threadIdx.x >> 6;
  constexpr int KPL = (DOUT == 64) ? 64 : 32;  // k-range handled per lane
  const int d = (DOUT == 64) ? lane : (lane & 31);
  const int sub = (DOUT == 64) ? 0 : (lane >> 5);
  const int kbase = sub * KPL;

  float wl[KPL], wr[KPL];
#pragma unroll
  for (int k = 0; k < KPL; ++k) {
    wl[k] = Wl[(kbase + k) * DOUT + d];
    wr[k] = Wr[(kbase + k) * DOUT + d];
  }
  const float bv = bl[d];

  __shared__ __align__(16) float rowbuf[4][2][64];
  float* srow = &rowbuf[wid][0][0];
  float* xrow = &rowbuf[wid][1][0];

  const int nWaves = gridDim.x * 4;
  for (int node = blockIdx.x * 4 + wid; node < NN; node += nWaves) {
    const int r0 = rowptr[node];
    const int r1 = rowptr[node + 1];
    float s0 = 0.f, s1 = 0.f, s2 = 0.f, s3 = 0.f;
    int e = r0;
    for (; e + 3 < r1; e += 4) {
      const int n0 = eidx[e], n1 = eidx[e + 1], n2 = eidx[e + 2], n3 = eidx[e + 3];
      s0 += xin[(size_t)n0 * 64 + lane];
      s1 += xin[(size_t)n1 * 64 + lane];
      s2 += xin[(size_t)n2 * 64 + lane];
      s3 += xin[(size_t)n3 * 64 + lane];
    }
    for (; e < r1; ++e) s0 += xin[(size_t)eidx[e] * 64 + lane];
    float s = (s0 + s1) + (s2 + s3);
    const int deg = r1 - r0;
    s *= (deg > 0) ? (1.f / (float)deg) : 1.f;  // mean with max(cnt,1)

    srow[lane] = s;
    xrow[lane] = xin[(size_t)node * 64 + lane];
    // wave-local LDS round-trip; compiler inserts lgkmcnt ordering.

    float acc = (sub == 0) ? bv : 0.f;
    const float4* s4 = reinterpret_cast<const float4*>(srow + kbase);
    const float4* x4 = reinterpret_cast<const float4*>(xrow + kbase);
#pragma unroll
    for (int i = 0; i < KPL / 4; ++i) {
      const float4 sv = s4[i];
      const float4 xv = x4[i];
      acc = fmaf(sv.x, wl[4 * i + 0], acc);
      acc = fmaf(sv.y, wl[4 * i + 1], acc);
      acc = fmaf(sv.z, wl[4 * i + 2], acc);
      acc = fmaf(sv.w, wl[4 * i + 3], acc);
      acc = fmaf(xv.x, wr[4 * i + 0], acc);
      acc = fmaf(xv.y, wr[4 * i + 1], acc);
      acc = fmaf(xv.z, wr[4 * i + 2], acc);
      acc = fmaf(xv.w, wr[4 * i + 3], acc);
    }
    if (DOUT == 32) {
      acc += __shfl_xor(acc, 32);
      if (lane < 32) out[(size_t)node * 32 + lane] = acc;
    } else {
      out[(size_t)node * 64 + lane] = RELU ? fmaxf(acc, 0.f) : acc;
    }
  }
}

// ---------------------------------------------------------------------------
extern "C" void kernel_launch(void* const* d_in, const int* in_sizes, int n_in,
                              void* d_out, int out_size, void* d_ws, size_t ws_size,
                              hipStream_t stream) {
  const float* product_x = (const float*)d_in[0];
  const float* user_emb = (const float*)d_in[1];
  const float* brand_emb = (const float*)d_in[2];
  const float* cat_emb = (const float*)d_in[3];
  const float* shop_emb = (const float*)d_in[4];
  const float* proj_W = (const float*)d_in[5];
  const float* proj_b = (const float*)d_in[6];
  const float* c1_Wl = (const float*)d_in[7];
  const float* c1_bl = (const float*)d_in[8];
  const float* c1_Wr = (const float*)d_in[9];
  const float* c2_Wl = (const float*)d_in[10];
  const float* c2_bl = (const float*)d_in[11];
  const float* c2_Wr = (const float*)d_in[12];
  const int* pb_src = (const int*)d_in[13];
  const int* pb_dst = (const int*)d_in[14];
  const int* pc_src = (const int*)d_in[15];
  const int* pc_dst = (const int*)d_in[16];
  const int* ps_src = (const int*)d_in[17];
  const int* ps_dst = (const int*)d_in[18];
  const int* up_src = (const int*)d_in[19];
  const int* up_dst = (const int*)d_in[20];
  const int nPB = in_sizes[13], nPC = in_sizes[15], nPS = in_sizes[17], nUP = in_sizes[19];
  const int nDirected = 2 * (nPB + nPC + nPS + nUP);

  // workspace layout
  float* x = (float*)d_ws;                         // [NN*64]
  float* out1 = x + (size_t)NN * 64;               // [NN*64]
  int* eidx = (int*)(out1 + (size_t)NN * 64);      // [nDirected]
  int* rowptr = eidx + nDirected;                  // [NN+1]
  int* cnt = rowptr + (NN + 1);                    // [NN]
  int* cursor = cnt + NN;                          // [NN]
  int* blockSums = cursor + NN;                    // [512]

  hipMemsetAsync(cnt, 0, NN * sizeof(int), stream);
  hipMemsetAsync(cursor, 0, NN * sizeof(int), stream);

  degree_kernel<<<(nPB + 255) / 256, 256, 0, stream>>>(pb_src, pb_dst, nPB, 0, OFF_B, cnt);
  degree_kernel<<<(nPC + 255) / 256, 256, 0, stream>>>(pc_src, pc_dst, nPC, 0, OFF_C, cnt);
  degree_kernel<<<(nPS + 255) / 256, 256, 0, stream>>>(ps_src, ps_dst, nPS, 0, OFF_S, cnt);
  degree_kernel<<<(nUP + 255) / 256, 256, 0, stream>>>(up_src, up_dst, nUP, OFF_U, 0, cnt);

  const int nb = (NN + 1023) / 1024;  // 301
  scan1_kernel<<<nb, 256, 0, stream>>>(cnt, blockSums, NN);
  scan2_kernel<<<1, 512, 0, stream>>>(blockSums, nb);
  scan3_kernel<<<nb, 256, 0, stream>>>(cnt, blockSums, rowptr, NN);

  fill_kernel<<<(nPB + 255) / 256, 256, 0, stream>>>(pb_src, pb_dst, nPB, 0, OFF_B, rowptr, cursor, eidx);
  fill_kernel<<<(nPC + 255) / 256, 256, 0, stream>>>(pc_src, pc_dst, nPC, 0, OFF_C, rowptr, cursor, eidx);
  fill_kernel<<<(nPS + 255) / 256, 256, 0, stream>>>(ps_src, ps_dst, nPS, 0, OFF_S, rowptr, cursor, eidx);
  fill_kernel<<<(nUP + 255) / 256, 256, 0, stream>>>(up_src, up_dst, nUP, OFF_U, 0, rowptr, cursor, eidx);

  proj_kernel<<<6250, 256, 0, stream>>>(product_x, proj_W, proj_b, x);
  hipMemcpyAsync(x + (size_t)OFF_U * 64, user_emb, (size_t)NU * 64 * sizeof(float),
                 hipMemcpyDeviceToDevice, stream);
  hipMemcpyAsync(x + (size_t)OFF_B * 64, brand_emb, (size_t)NBR * 64 * sizeof(float),
                 hipMemcpyDeviceToDevice, stream);
  hipMemcpyAsync(x + (size_t)OFF_C * 64, cat_emb, (size_t)NCAT * 64 * sizeof(float),
                 hipMemcpyDeviceToDevice, stream);
  hipMemcpyAsync(x + (size_t)OFF_S * 64, shop_emb, (size_t)NSH * 64 * sizeof(float),
                 hipMemcpyDeviceToDevice, stream);

  agg_fin_kernel<64, true><<<2048, 256, 0, stream>>>(rowptr, eidx, x, c1_Wl, c1_bl, c1_Wr, out1);
  agg_fin_kernel<32, false><<<2048, 256, 0, stream>>>(rowptr, eidx, out1, c2_Wl, c2_bl, c2_Wr,
                                                      (float*)d_out);
}

// Round 2
// 1426.177 us; speedup vs baseline: 1.3757x; 1.3757x over previous
//
#include <hip/hip_runtime.h>

#define NP 200000
#define NU 100000
#define NBR 5000
#define NCAT 2000
#define NSH 1000
#define NN (NP + NU + NBR + NCAT + NSH) /* 308000 */
#define OFF_U NP
#define OFF_B (NP + NU)
#define OFF_C (NP + NU + NBR)
#define OFF_S (NP + NU + NBR + NCAT)

typedef unsigned short u16;

__device__ __forceinline__ u16 f2bf(float f) {
  union { float f; unsigned u; } v;
  v.f = f;
  unsigned r = (v.u + 0x7fffu + ((v.u >> 16) & 1u)) >> 16;  // RNE
  return (u16)r;
}
__device__ __forceinline__ float bf2f(u16 u) {
  union { unsigned u; float f; } v;
  v.u = ((unsigned)u) << 16;
  return v.f;
}

// ---------------------------------------------------------------------------
// Projection GEMM: xb[r][c] = bf16(relu(px[r][:] @ W[:][c] + b[c])), r<NP.
// Block = 256 thr computes 128 rows x 64 cols. A tile + W chunk staged in LDS
// (coalesced); per-thread 8x4 register tile -> 128 FMAs per 12 ds_read_b128.
// ---------------------------------------------------------------------------
__global__ __launch_bounds__(256) void proj_gemm_kernel(
    const float* __restrict__ px, const float* __restrict__ W,
    const float* __restrict__ bias, u16* __restrict__ xb) {
  __shared__ __align__(16) float lA[128 * 68];  // stride 68 floats (16B-aligned)
  __shared__ __align__(16) float lW[64 * 64];
  const int t = threadIdx.x;
  const int row0 = blockIdx.x * 128;
  const int c0 = (t & 15) * 4;
  const int rg = t >> 4;  // 0..15, rows rg*8..rg*8+7

  float acc[8][4];
#pragma unroll
  for (int r = 0; r < 8; ++r)
#pragma unroll
    for (int c = 0; c < 4; ++c) acc[r][c] = 0.f;

  for (int k0 = 0; k0 < 384; k0 += 64) {
    __syncthreads();
#pragma unroll
    for (int i = 0; i < 8; ++i) {  // stage A[128][64]
      const int idx = i * 256 + t;
      const int r = idx >> 4, q = idx & 15;
      const int grow = row0 + r;
      float4 v = make_float4(0.f, 0.f, 0.f, 0.f);
      if (grow < NP)
        v = *reinterpret_cast<const float4*>(px + (size_t)grow * 384 + k0 + q * 4);
      *reinterpret_cast<float4*>(&lA[r * 68 + q * 4]) = v;
    }
#pragma unroll
    for (int i = 0; i < 4; ++i) {  // stage W[64][64]
      const int idx = i * 256 + t;
      const int r = idx >> 4, q = idx & 15;
      const float4 v = *reinterpret_cast<const float4*>(W + (size_t)(k0 + r) * 64 + q * 4);
      *reinterpret_cast<float4*>(&lW[r * 64 + q * 4]) = v;
    }
    __syncthreads();
#pragma unroll
    for (int kq = 0; kq < 16; ++kq) {
      float4 w4[4];
#pragma unroll
      for (int j = 0; j < 4; ++j)
        w4[j] = *reinterpret_cast<const float4*>(&lW[(kq * 4 + j) * 64 + c0]);
#pragma unroll
      for (int r = 0; r < 8; ++r) {
        const float4 a = *reinterpret_cast<const float4*>(&lA[(rg * 8 + r) * 68 + kq * 4]);
        acc[r][0] = fmaf(a.x, w4[0].x, acc[r][0]);
        acc[r][1] = fmaf(a.x, w4[0].y, acc[r][1]);
        acc[r][2] = fmaf(a.x, w4[0].z, acc[r][2]);
        acc[r][3] = fmaf(a.x, w4[0].w, acc[r][3]);
        acc[r][0] = fmaf(a.y, w4[1].x, acc[r][0]);
        acc[r][1] = fmaf(a.y, w4[1].y, acc[r][1]);
        acc[r][2] = fmaf(a.y, w4[1].z, acc[r][2]);
        acc[r][3] = fmaf(a.y, w4[1].w, acc[r][3]);
        acc[r][0] = fmaf(a.z, w4[2].x, acc[r][0]);
        acc[r][1] = fmaf(a.z, w4[2].y, acc[r][1]);
        acc[r][2] = fmaf(a.z, w4[2].z, acc[r][2]);
        acc[r][3] = fmaf(a.z, w4[2].w, acc[r][3]);
        acc[r][0] = fmaf(a.w, w4[3].x, acc[r][0]);
        acc[r][1] = fmaf(a.w, w4[3].y, acc[r][1]);
        acc[r][2] = fmaf(a.w, w4[3].z, acc[r][2]);
        acc[r][3] = fmaf(a.w, w4[3].w, acc[r][3]);
      }
    }
  }
  const float b0 = bias[c0 + 0], b1 = bias[c0 + 1], b2 = bias[c0 + 2], b3 = bias[c0 + 3];
#pragma unroll
  for (int r = 0; r < 8; ++r) {
    const int grow = row0 + rg * 8 + r;
    if (grow < NP) {
      ushort4 o;
      o.x = f2bf(fmaxf(acc[r][0] + b0, 0.f));
      o.y = f2bf(fmaxf(acc[r][1] + b1, 0.f));
      o.z = f2bf(fmaxf(acc[r][2] + b2, 0.f));
      o.w = f2bf(fmaxf(acc[r][3] + b3, 0.f));
      *reinterpret_cast<ushort4*>(&xb[(size_t)grow * 64 + c0]) = o;
    }
  }
}

// fp32 -> bf16 table conversion (embeddings into x)
__global__ void cvt_f32_bf16_kernel(const float* __restrict__ in, u16* __restrict__ out,
                                    int n4) {
  const int i = blockIdx.x * 256 + threadIdx.x;
  if (i >= n4) return;
  const float4 v = reinterpret_cast<const float4*>(in)[i];
  ushort4 o;
  o.x = f2bf(v.x);
  o.y = f2bf(v.y);
  o.z = f2bf(v.z);
  o.w = f2bf(v.w);
  reinterpret_cast<ushort4*>(out)[i] = o;
}

// ---------------------------------------------------------------------------
// Degree count over one relation (both directions; int atomics).
// ---------------------------------------------------------------------------
__global__ void degree_kernel(const int* __restrict__ src, const int* __restrict__ dst,
                              int n, int offS, int offD, int* __restrict__ cnt) {
  int e = blockIdx.x * 256 + threadIdx.x;
  if (e >= n) return;
  atomicAdd(&cnt[src[e] + offS], 1);
  atomicAdd(&cnt[dst[e] + offD], 1);
}

// 3-kernel exclusive scan cnt[NN] -> rowptr[NN+1]
__global__ __launch_bounds__(256) void scan1_kernel(const int* __restrict__ cnt,
                                                    int* __restrict__ blockSums, int n) {
  __shared__ int sdata[256];
  const int base = blockIdx.x * 1024;
  int s = 0;
  for (int i = threadIdx.x; i < 1024; i += 256) {
    int idx = base + i;
    if (idx < n) s += cnt[idx];
  }
  sdata[threadIdx.x] = s;
  __syncthreads();
  for (int off = 128; off > 0; off >>= 1) {
    if (threadIdx.x < off) sdata[threadIdx.x] += sdata[threadIdx.x + off];
    __syncthreads();
  }
  if (threadIdx.x == 0) blockSums[blockIdx.x] = sdata[0];
}

__global__ __launch_bounds__(512) void scan2_kernel(int* __restrict__ blockSums, int nb) {
  __shared__ int sd[512];
  const int t = threadIdx.x;
  const int v = (t < nb) ? blockSums[t] : 0;
  sd[t] = v;
  __syncthreads();
  for (int off = 1; off < 512; off <<= 1) {
    int add = (t >= off) ? sd[t - off] : 0;
    __syncthreads();
    sd[t] += add;
    __syncthreads();
  }
  if (t < nb) blockSums[t] = sd[t] - v;  // exclusive
}

__global__ __launch_bounds__(256) void scan3_kernel(const int* __restrict__ cnt,
                                                    const int* __restrict__ blockSums,
                                                    int* __restrict__ rowptr, int n) {
  __shared__ int wsum[4];
  const int base = blockIdx.x * 1024;
  const int t = threadIdx.x, lane = t & 63, wid = t >> 6;
  const int idx0 = base + t * 4;
  int v[4];
#pragma unroll
  for (int j = 0; j < 4; ++j) {
    int idx = idx0 + j;
    v[j] = (idx < n) ? cnt[idx] : 0;
  }
  const int s = v[0] + v[1] + v[2] + v[3];
  int incl = s;
  for (int off = 1; off < 64; off <<= 1) {
    int tt = __shfl_up(incl, off);
    if (lane >= off) incl += tt;
  }
  if (lane == 63) wsum[wid] = incl;
  __syncthreads();
  int wOff = 0;
#pragma unroll
  for (int w = 0; w < 4; ++w)
    if (w < wid) wOff += wsum[w];
  int run = blockSums[blockIdx.x] + wOff + (incl - s);
#pragma unroll
  for (int j = 0; j < 4; ++j) {
    int idx = idx0 + j;
    if (idx < n) {
      rowptr[idx] = run;
      run += v[j];
      if (idx == n - 1) rowptr[n] = run;
    }
  }
}

// Bucket-scatter in-neighbor lists (CSR adjacency).
__global__ void fill_kernel(const int* __restrict__ src, const int* __restrict__ dst,
                            int n, int offS, int offD, const int* __restrict__ rowptr,
                            int* __restrict__ cursor, int* __restrict__ eidx) {
  int e = blockIdx.x * 256 + threadIdx.x;
  if (e >= n) return;
  const int a = src[e] + offS;
  const int b = dst[e] + offD;
  int pa = atomicAdd(&cursor[a], 1);
  eidx[rowptr[a] + pa] = b;
  int pb = atomicAdd(&cursor[b], 1);
  eidx[rowptr[b] + pb] = a;
}

// ---------------------------------------------------------------------------
// Fused mean-aggregate + SAGE linear (bf16 feature table, fp32 accum):
//   out = act( (mean_{j in N(i)} xin_j) @ Wl + bl + xin_i @ Wr )
// One wave per node; W columns in VGPRs (static unroll).
// DOUT=64 -> bf16 out (relu); DOUT=32 -> fp32 out (no relu).
// ---------------------------------------------------------------------------
template <int DOUT, bool RELU, typename OutT>
__global__ __launch_bounds__(256) void agg_fin_kernel(
    const int* __restrict__ rowptr, const int* __restrict__ eidx,
    const u16* __restrict__ xin, const float* __restrict__ Wl,
    const float* __restrict__ bl, const float* __restrict__ Wr,
    OutT* __restrict__ out) {
  const int lane = threadIdx.x & 63;
  const int wid = threadIdx.x >> 6;
  constexpr int KPL = (DOUT == 64) ? 64 : 32;
  const int d = (DOUT == 64) ? lane : (lane & 31);
  const int sub = (DOUT == 64) ? 0 : (lane >> 5);
  const int kbase = sub * KPL;

  float wl[KPL], wr[KPL];
#pragma unroll
  for (int k = 0; k < KPL; ++k) {
    wl[k] = Wl[(kbase + k) * DOUT + d];
    wr[k] = Wr[(kbase + k) * DOUT + d];
  }
  const float bv = bl[d];

  __shared__ __align__(16) float rowbuf[4][2][64];
  float* srow = &rowbuf[wid][0][0];
  float* xrow = &rowbuf[wid][1][0];

  const int nWaves = gridDim.x * 4;
  for (int node = blockIdx.x * 4 + wid; node < NN; node += nWaves) {
    const int r0 = rowptr[node];
    const int r1 = rowptr[node + 1];
    float s0 = 0.f, s1 = 0.f, s2 = 0.f, s3 = 0.f;
    int e = r0;
    for (; e + 3 < r1; e += 4) {
      const int n0 = eidx[e], n1 = eidx[e + 1], n2 = eidx[e + 2], n3 = eidx[e + 3];
      s0 += bf2f(xin[(size_t)n0 * 64 + lane]);
      s1 += bf2f(xin[(size_t)n1 * 64 + lane]);
      s2 += bf2f(xin[(size_t)n2 * 64 + lane]);
      s3 += bf2f(xin[(size_t)n3 * 64 + lane]);
    }
    for (; e < r1; ++e) s0 += bf2f(xin[(size_t)eidx[e] * 64 + lane]);
    float s = (s0 + s1) + (s2 + s3);
    const int deg = r1 - r0;
    s *= (deg > 0) ? (1.f / (float)deg) : 1.f;

    srow[lane] = s;
    xrow[lane] = bf2f(xin[(size_t)node * 64 + lane]);

    float acc = (sub == 0) ? bv : 0.f;
    const float4* s4 = reinterpret_cast<const float4*>(srow + kbase);
    const float4* x4 = reinterpret_cast<const float4*>(xrow + kbase);
#pragma unroll
    for (int i = 0; i < KPL / 4; ++i) {
      const float4 sv = s4[i];
      const float4 xv = x4[i];
      acc = fmaf(sv.x, wl[4 * i + 0], acc);
      acc = fmaf(sv.y, wl[4 * i + 1], acc);
      acc = fmaf(sv.z, wl[4 * i + 2], acc);
      acc = fmaf(sv.w, wl[4 * i + 3], acc);
      acc = fmaf(xv.x, wr[4 * i + 0], acc);
      acc = fmaf(xv.y, wr[4 * i + 1], acc);
      acc = fmaf(xv.z, wr[4 * i + 2], acc);
      acc = fmaf(xv.w, wr[4 * i + 3], acc);
    }
    if (DOUT == 32) {
      acc += __shfl_xor(acc, 32);
      if (lane < 32) ((float*)out)[(size_t)node * 32 + lane] = acc;
    } else {
      ((u16*)out)[(size_t)node * 64 + lane] = f2bf(RELU ? fmaxf(acc, 0.f) : acc);
    }
  }
}

// ---------------------------------------------------------------------------
extern "C" void kernel_launch(void* const* d_in, const int* in_sizes, int n_in,
                              void* d_out, int out_size, void* d_ws, size_t ws_size,
                              hipStream_t stream) {
  const float* product_x = (const float*)d_in[0];
  const float* user_emb = (const float*)d_in[1];
  const float* brand_emb = (const float*)d_in[2];
  const float* cat_emb = (const float*)d_in[3];
  const float* shop_emb = (const float*)d_in[4];
  const float* proj_W = (const float*)d_in[5];
  const float* proj_b = (const float*)d_in[6];
  const float* c1_Wl = (const float*)d_in[7];
  const float* c1_bl = (const float*)d_in[8];
  const float* c1_Wr = (const float*)d_in[9];
  const float* c2_Wl = (const float*)d_in[10];
  const float* c2_bl = (const float*)d_in[11];
  const float* c2_Wr = (const float*)d_in[12];
  const int* pb_src = (const int*)d_in[13];
  const int* pb_dst = (const int*)d_in[14];
  const int* pc_src = (const int*)d_in[15];
  const int* pc_dst = (const int*)d_in[16];
  const int* ps_src = (const int*)d_in[17];
  const int* ps_dst = (const int*)d_in[18];
  const int* up_src = (const int*)d_in[19];
  const int* up_dst = (const int*)d_in[20];
  const int nPB = in_sizes[13], nPC = in_sizes[15], nPS = in_sizes[17], nUP = in_sizes[19];
  const int nDirected = 2 * (nPB + nPC + nPS + nUP);

  // workspace layout
  u16* xb = (u16*)d_ws;                            // [NN*64] bf16
  u16* out1 = xb + (size_t)NN * 64;                // [NN*64] bf16
  int* eidx = (int*)(out1 + (size_t)NN * 64);      // [nDirected]
  int* rowptr = eidx + nDirected;                  // [NN+1]
  int* cnt = rowptr + (NN + 1);                    // [NN]
  int* cursor = cnt + NN;                          // [NN]
  int* blockSums = cursor + NN;                    // [512]

  hipMemsetAsync(cnt, 0, NN * sizeof(int), stream);
  hipMemsetAsync(cursor, 0, NN * sizeof(int), stream);

  degree_kernel<<<(nPB + 255) / 256, 256, 0, stream>>>(pb_src, pb_dst, nPB, 0, OFF_B, cnt);
  degree_kernel<<<(nPC + 255) / 256, 256, 0, stream>>>(pc_src, pc_dst, nPC, 0, OFF_C, cnt);
  degree_kernel<<<(nPS + 255) / 256, 256, 0, stream>>>(ps_src, ps_dst, nPS, 0, OFF_S, cnt);
  degree_kernel<<<(nUP + 255) / 256, 256, 0, stream>>>(up_src, up_dst, nUP, OFF_U, 0, cnt);

  const int nb = (NN + 1023) / 1024;  // 301
  scan1_kernel<<<nb, 256, 0, stream>>>(cnt, blockSums, NN);
  scan2_kernel<<<1, 512, 0, stream>>>(blockSums, nb);
  scan3_kernel<<<nb, 256, 0, stream>>>(cnt, blockSums, rowptr, NN);

  fill_kernel<<<(nPB + 255) / 256, 256, 0, stream>>>(pb_src, pb_dst, nPB, 0, OFF_B, rowptr, cursor, eidx);
  fill_kernel<<<(nPC + 255) / 256, 256, 0, stream>>>(pc_src, pc_dst, nPC, 0, OFF_C, rowptr, cursor, eidx);
  fill_kernel<<<(nPS + 255) / 256, 256, 0, stream>>>(ps_src, ps_dst, nPS, 0, OFF_S, rowptr, cursor, eidx);
  fill_kernel<<<(nUP + 255) / 256, 256, 0, stream>>>(up_src, up_dst, nUP, OFF_U, 0, rowptr, cursor, eidx);

  proj_gemm_kernel<<<(NP + 127) / 128, 256, 0, stream>>>(product_x, proj_W, proj_b, xb);
  cvt_f32_bf16_kernel<<<(NU * 16 + 255) / 256, 256, 0, stream>>>(user_emb, xb + (size_t)OFF_U * 64, NU * 16);
  cvt_f32_bf16_kernel<<<(NBR * 16 + 255) / 256, 256, 0, stream>>>(brand_emb, xb + (size_t)OFF_B * 64, NBR * 16);
  cvt_f32_bf16_kernel<<<(NCAT * 16 + 255) / 256, 256, 0, stream>>>(cat_emb, xb + (size_t)OFF_C * 64, NCAT * 16);
  cvt_f32_bf16_kernel<<<(NSH * 16 + 255) / 256, 256, 0, stream>>>(shop_emb, xb + (size_t)OFF_S * 64, NSH * 16);

  agg_fin_kernel<64, true, u16><<<2048, 256, 0, stream>>>(rowptr, eidx, xb, c1_Wl, c1_bl, c1_Wr, out1);
  agg_fin_kernel<32, false, float><<<2048, 256, 0, stream>>>(rowptr, eidx, out1, c2_Wl, c2_bl, c2_Wr,
                                                             (float*)d_out);
}

// Round 3
// 1044.122 us; speedup vs baseline: 1.8791x; 1.3659x over previous
//
#include <hip/hip_runtime.h>

#define NP 200000
#define NU 100000
#define NBR 5000
#define NCAT 2000
#define NSH 1000
#define NN (NP + NU + NBR + NCAT + NSH) /* 308000 */
#define OFF_U NP
#define OFF_B (NP + NU)
#define OFF_C (NP + NU + NBR)
#define OFF_S (NP + NU + NBR + NCAT)

typedef unsigned short u16;
typedef unsigned int u32;

__device__ __forceinline__ u16 f2bf(float f) {
  union { float f; unsigned u; } v;
  v.f = f;
  unsigned r = (v.u + 0x7fffu + ((v.u >> 16) & 1u)) >> 16;  // RNE
  return (u16)r;
}
__device__ __forceinline__ float uasf(u32 u) {
  union { u32 u; float f; } v;
  v.u = u;
  return v.f;
}

// ---------------------------------------------------------------------------
// Projection GEMM: xb[r][c] = bf16(relu(px[r][:] @ W[:][c] + b[c])), r<NP.
// ---------------------------------------------------------------------------
__global__ __launch_bounds__(256) void proj_gemm_kernel(
    const float* __restrict__ px, const float* __restrict__ W,
    const float* __restrict__ bias, u16* __restrict__ xb) {
  __shared__ __align__(16) float lA[128 * 68];
  __shared__ __align__(16) float lW[64 * 64];
  const int t = threadIdx.x;
  const int row0 = blockIdx.x * 128;
  const int c0 = (t & 15) * 4;
  const int rg = t >> 4;

  float acc[8][4];
#pragma unroll
  for (int r = 0; r < 8; ++r)
#pragma unroll
    for (int c = 0; c < 4; ++c) acc[r][c] = 0.f;

  for (int k0 = 0; k0 < 384; k0 += 64) {
    __syncthreads();
#pragma unroll
    for (int i = 0; i < 8; ++i) {
      const int idx = i * 256 + t;
      const int r = idx >> 4, q = idx & 15;
      const int grow = row0 + r;
      float4 v = make_float4(0.f, 0.f, 0.f, 0.f);
      if (grow < NP)
        v = *reinterpret_cast<const float4*>(px + (size_t)grow * 384 + k0 + q * 4);
      *reinterpret_cast<float4*>(&lA[r * 68 + q * 4]) = v;
    }
#pragma unroll
    for (int i = 0; i < 4; ++i) {
      const int idx = i * 256 + t;
      const int r = idx >> 4, q = idx & 15;
      const float4 v = *reinterpret_cast<const float4*>(W + (size_t)(k0 + r) * 64 + q * 4);
      *reinterpret_cast<float4*>(&lW[r * 64 + q * 4]) = v;
    }
    __syncthreads();
#pragma unroll
    for (int kq = 0; kq < 16; ++kq) {
      float4 w4[4];
#pragma unroll
      for (int j = 0; j < 4; ++j)
        w4[j] = *reinterpret_cast<const float4*>(&lW[(kq * 4 + j) * 64 + c0]);
#pragma unroll
      for (int r = 0; r < 8; ++r) {
        const float4 a = *reinterpret_cast<const float4*>(&lA[(rg * 8 + r) * 68 + kq * 4]);
        acc[r][0] = fmaf(a.x, w4[0].x, acc[r][0]);
        acc[r][1] = fmaf(a.x, w4[0].y, acc[r][1]);
        acc[r][2] = fmaf(a.x, w4[0].z, acc[r][2]);
        acc[r][3] = fmaf(a.x, w4[0].w, acc[r][3]);
        acc[r][0] = fmaf(a.y, w4[1].x, acc[r][0]);
        acc[r][1] = fmaf(a.y, w4[1].y, acc[r][1]);
        acc[r][2] = fmaf(a.y, w4[1].z, acc[r][2]);
        acc[r][3] = fmaf(a.y, w4[1].w, acc[r][3]);
        acc[r][0] = fmaf(a.z, w4[2].x, acc[r][0]);
        acc[r][1] = fmaf(a.z, w4[2].y, acc[r][1]);
        acc[r][2] = fmaf(a.z, w4[2].z, acc[r][2]);
        acc[r][3] = fmaf(a.z, w4[2].w, acc[r][3]);
        acc[r][0] = fmaf(a.w, w4[3].x, acc[r][0]);
        acc[r][1] = fmaf(a.w, w4[3].y, acc[r][1]);
        acc[r][2] = fmaf(a.w, w4[3].z, acc[r][2]);
        acc[r][3] = fmaf(a.w, w4[3].w, acc[r][3]);
      }
    }
  }
  const float b0 = bias[c0 + 0], b1 = bias[c0 + 1], b2 = bias[c0 + 2], b3 = bias[c0 + 3];
#pragma unroll
  for (int r = 0; r < 8; ++r) {
    const int grow = row0 + rg * 8 + r;
    if (grow < NP) {
      ushort4 o;
      o.x = f2bf(fmaxf(acc[r][0] + b0, 0.f));
      o.y = f2bf(fmaxf(acc[r][1] + b1, 0.f));
      o.z = f2bf(fmaxf(acc[r][2] + b2, 0.f));
      o.w = f2bf(fmaxf(acc[r][3] + b3, 0.f));
      *reinterpret_cast<ushort4*>(&xb[(size_t)grow * 64 + c0]) = o;
    }
  }
}

// ---------------------------------------------------------------------------
// Fused fp32->bf16 conversion of all 4 embedding tables into xb.
// ---------------------------------------------------------------------------
__global__ void cvt_emb_kernel(const float* __restrict__ ue, const float* __restrict__ be,
                               const float* __restrict__ ce, const float* __restrict__ se,
                               u16* __restrict__ xb) {
  const int i = blockIdx.x * 256 + threadIdx.x;  // float4-quad index
  const int totalQ = (NU + NBR + NCAT + NSH) * 16;
  if (i >= totalQ) return;
  const int row = i >> 4, q = i & 15;
  const float* src;
  int lrow;
  if (row < NU) {
    src = ue; lrow = row;
  } else if (row < NU + NBR) {
    src = be; lrow = row - NU;
  } else if (row < NU + NBR + NCAT) {
    src = ce; lrow = row - NU - NBR;
  } else {
    src = se; lrow = row - NU - NBR - NCAT;
  }
  const float4 v = reinterpret_cast<const float4*>(src)[(size_t)lrow * 16 + q];
  ushort4 o;
  o.x = f2bf(v.x);
  o.y = f2bf(v.y);
  o.z = f2bf(v.z);
  o.w = f2bf(v.w);
  reinterpret_cast<ushort4*>(xb + (size_t)(OFF_U + row) * 64)[q] = o;
}

// ---------------------------------------------------------------------------
// CSR build: fused degree count over all 4 relations.
// ---------------------------------------------------------------------------
__global__ void degree_all_kernel(const int* __restrict__ pbs, const int* __restrict__ pbd,
                                  const int* __restrict__ pcs, const int* __restrict__ pcd,
                                  const int* __restrict__ pss, const int* __restrict__ psd,
                                  const int* __restrict__ ups, const int* __restrict__ upd,
                                  int nPB, int nPC, int nPS, int nUP, int* __restrict__ cnt) {
  int e = blockIdx.x * 256 + threadIdx.x;
  int a, b;
  if (e < nPB) {
    a = pbs[e]; b = pbd[e] + OFF_B;
  } else {
    e -= nPB;
    if (e < nPC) {
      a = pcs[e]; b = pcd[e] + OFF_C;
    } else {
      e -= nPC;
      if (e < nPS) {
        a = pss[e]; b = psd[e] + OFF_S;
      } else {
        e -= nPS;
        if (e >= nUP) return;
        a = ups[e] + OFF_U; b = upd[e];
      }
    }
  }
  atomicAdd(&cnt[a], 1);
  atomicAdd(&cnt[b], 1);
}

// 3-kernel exclusive scan cnt[NN] -> rowptr[NN+1]
__global__ __launch_bounds__(256) void scan1_kernel(const int* __restrict__ cnt,
                                                    int* __restrict__ blockSums, int n) {
  __shared__ int sdata[256];
  const int base = blockIdx.x * 1024;
  int s = 0;
  for (int i = threadIdx.x; i < 1024; i += 256) {
    int idx = base + i;
    if (idx < n) s += cnt[idx];
  }
  sdata[threadIdx.x] = s;
  __syncthreads();
  for (int off = 128; off > 0; off >>= 1) {
    if (threadIdx.x < off) sdata[threadIdx.x] += sdata[threadIdx.x + off];
    __syncthreads();
  }
  if (threadIdx.x == 0) blockSums[blockIdx.x] = sdata[0];
}

__global__ __launch_bounds__(512) void scan2_kernel(int* __restrict__ blockSums, int nb) {
  __shared__ int sd[512];
  const int t = threadIdx.x;
  const int v = (t < nb) ? blockSums[t] : 0;
  sd[t] = v;
  __syncthreads();
  for (int off = 1; off < 512; off <<= 1) {
    int add = (t >= off) ? sd[t - off] : 0;
    __syncthreads();
    sd[t] += add;
    __syncthreads();
  }
  if (t < nb) blockSums[t] = sd[t] - v;  // exclusive
}

__global__ __launch_bounds__(256) void scan3_kernel(const int* __restrict__ cnt,
                                                    const int* __restrict__ blockSums,
                                                    int* __restrict__ rowptr, int n) {
  __shared__ int wsum[4];
  const int base = blockIdx.x * 1024;
  const int t = threadIdx.x, lane = t & 63, wid = t >> 6;
  const int idx0 = base + t * 4;
  int v[4];
#pragma unroll
  for (int j = 0; j < 4; ++j) {
    int idx = idx0 + j;
    v[j] = (idx < n) ? cnt[idx] : 0;
  }
  const int s = v[0] + v[1] + v[2] + v[3];
  int incl = s;
  for (int off = 1; off < 64; off <<= 1) {
    int tt = __shfl_up(incl, off);
    if (lane >= off) incl += tt;
  }
  if (lane == 63) wsum[wid] = incl;
  __syncthreads();
  int wOff = 0;
#pragma unroll
  for (int w = 0; w < 4; ++w)
    if (w < wid) wOff += wsum[w];
  int run = blockSums[blockIdx.x] + wOff + (incl - s);
#pragma unroll
  for (int j = 0; j < 4; ++j) {
    int idx = idx0 + j;
    if (idx < n) {
      rowptr[idx] = run;
      run += v[j];
      if (idx == n - 1) rowptr[n] = run;
    }
  }
}

// Fused bucket-scatter of in-neighbor lists over all 4 relations.
__global__ void fill_all_kernel(const int* __restrict__ pbs, const int* __restrict__ pbd,
                                const int* __restrict__ pcs, const int* __restrict__ pcd,
                                const int* __restrict__ pss, const int* __restrict__ psd,
                                const int* __restrict__ ups, const int* __restrict__ upd,
                                int nPB, int nPC, int nPS, int nUP,
                                const int* __restrict__ rowptr, int* __restrict__ cursor,
                                int* __restrict__ eidx) {
  int e = blockIdx.x * 256 + threadIdx.x;
  int a, b;
  if (e < nPB) {
    a = pbs[e]; b = pbd[e] + OFF_B;
  } else {
    e -= nPB;
    if (e < nPC) {
      a = pcs[e]; b = pcd[e] + OFF_C;
    } else {
      e -= nPC;
      if (e < nPS) {
        a = pss[e]; b = psd[e] + OFF_S;
      } else {
        e -= nPS;
        if (e >= nUP) return;
        a = ups[e] + OFF_U; b = upd[e];
      }
    }
  }
  int pa = atomicAdd(&cursor[a], 1);
  eidx[rowptr[a] + pa] = b;
  int pb = atomicAdd(&cursor[b], 1);
  eidx[rowptr[b] + pb] = a;
}

// ---------------------------------------------------------------------------
// Gather-mean: sout[node][:] = bf16(mean_{j in N(node)} xin[j][:]).
// Half-wave per edge: lane = (h=lane>>5, q=lane&31); each lane loads u32
// (2 bf16 dims); 8 edges in flight per iteration; clamped-address
// predication (branchless). fp32 accumulate.
// ---------------------------------------------------------------------------
__global__ __launch_bounds__(256) void gather_mean_kernel(
    const int* __restrict__ rowptr, const int* __restrict__ eidx,
    const u32* __restrict__ xin, u32* __restrict__ sout) {
  const int lane = threadIdx.x & 63;
  const int q = lane & 31;
  const int h = lane >> 5;
  const int wid0 = blockIdx.x * 4 + (threadIdx.x >> 6);
  const int nW = gridDim.x * 4;
  for (int node = wid0; node < NN; node += nW) {
    const int r0 = rowptr[node], r1 = rowptr[node + 1];
    float sl = 0.f, sh = 0.f;
    for (int e = r0; e < r1; e += 8) {
      int nj[4];
#pragma unroll
      for (int j = 0; j < 4; ++j) {
        const int ee = e + 2 * j + h;
        const int ec = (ee < r1 - 1) ? ee : (r1 - 1);
        nj[j] = eidx[ec];
      }
      u32 rv[4];
#pragma unroll
      for (int j = 0; j < 4; ++j) {
        u32 r = xin[(size_t)nj[j] * 32 + q];
        rv[j] = (e + 2 * j + h < r1) ? r : 0u;
      }
#pragma unroll
      for (int j = 0; j < 4; ++j) {
        sl += uasf(rv[j] << 16);
        sh += uasf(rv[j] & 0xffff0000u);
      }
    }
    sl += __shfl_xor(sl, 32);
    sh += __shfl_xor(sh, 32);
    if (h == 0) {
      const int deg = r1 - r0;
      const float inv = (deg > 0) ? (1.f / (float)deg) : 1.f;
      const u32 o = (u32)f2bf(sl * inv) | ((u32)f2bf(sh * inv) << 16);
      sout[(size_t)node * 32 + q] = o;
    }
  }
}

// ---------------------------------------------------------------------------
// Dense layer GEMM: out = act(S @ Wl + bl + X @ Wr), S,X bf16 [NN][64].
// 128-row tile; S,X tiles bf16 in LDS; Wl,Wr fp32 in LDS.
// DOUT=64 -> bf16 out + relu; DOUT=32 -> fp32 out.
// ---------------------------------------------------------------------------
template <int DOUT, bool RELU>
__global__ __launch_bounds__(256) void layer_gemm_kernel(
    const u32* __restrict__ S, const u32* __restrict__ X,
    const float* __restrict__ Wl, const float* __restrict__ bl,
    const float* __restrict__ Wr, void* __restrict__ outv) {
  constexpr int NC = DOUT / 4;   // col groups (16 or 8)
  constexpr int NR = 256 / NC;   // row groups (16 or 32)
  constexpr int R = 128 / NR;    // rows per thread (8 or 4)
  __shared__ __align__(16) u32 lS[128 * 32];
  __shared__ __align__(16) u32 lX[128 * 32];
  __shared__ __align__(16) float lWl[64 * DOUT];
  __shared__ __align__(16) float lWr[64 * DOUT];
  const int t = threadIdx.x;
  const int row0 = blockIdx.x * 128;

#pragma unroll
  for (int i = 0; i < (64 * DOUT) / 1024; ++i) {  // stage W (float4)
    const int idx = i * 256 + t;
    reinterpret_cast<float4*>(lWl)[idx] = reinterpret_cast<const float4*>(Wl)[idx];
    reinterpret_cast<float4*>(lWr)[idx] = reinterpret_cast<const float4*>(Wr)[idx];
  }
#pragma unroll
  for (int i = 0; i < 4; ++i) {  // stage S, X tiles (uint4)
    const int idx = i * 256 + t;
    const int r = idx >> 3, c = idx & 7;
    uint4 vs = make_uint4(0u, 0u, 0u, 0u), vx = vs;
    if (row0 + r < NN) {
      vs = reinterpret_cast<const uint4*>(S)[(size_t)(row0 + r) * 8 + c];
      vx = reinterpret_cast<const uint4*>(X)[(size_t)(row0 + r) * 8 + c];
    }
    reinterpret_cast<uint4*>(lS)[idx] = vs;
    reinterpret_cast<uint4*>(lX)[idx] = vx;
  }
  __syncthreads();

  const int cg = t % NC, rg = t / NC;
  const int c0 = cg * 4;
  float acc[R][4];
#pragma unroll
  for (int r = 0; r < R; ++r)
#pragma unroll
    for (int c = 0; c < 4; ++c) acc[r][c] = 0.f;

  for (int kq = 0; kq < 16; ++kq) {
    float4 wl4[4], wr4[4];
#pragma unroll
    for (int j = 0; j < 4; ++j) {
      wl4[j] = *reinterpret_cast<const float4*>(&lWl[(kq * 4 + j) * DOUT + c0]);
      wr4[j] = *reinterpret_cast<const float4*>(&lWr[(kq * 4 + j) * DOUT + c0]);
    }
#pragma unroll
    for (int r = 0; r < R; ++r) {
      const int row = rg * R + r;
      const uint2 sv = *reinterpret_cast<const uint2*>(&lS[row * 32 + kq * 2]);
      const uint2 xv = *reinterpret_cast<const uint2*>(&lX[row * 32 + kq * 2]);
      const float sf[4] = {uasf(sv.x << 16), uasf(sv.x & 0xffff0000u),
                           uasf(sv.y << 16), uasf(sv.y & 0xffff0000u)};
      const float xf[4] = {uasf(xv.x << 16), uasf(xv.x & 0xffff0000u),
                           uasf(xv.y << 16), uasf(xv.y & 0xffff0000u)};
#pragma unroll
      for (int j = 0; j < 4; ++j) {
        acc[r][0] = fmaf(sf[j], wl4[j].x, acc[r][0]);
        acc[r][1] = fmaf(sf[j], wl4[j].y, acc[r][1]);
        acc[r][2] = fmaf(sf[j], wl4[j].z, acc[r][2]);
        acc[r][3] = fmaf(sf[j], wl4[j].w, acc[r][3]);
        acc[r][0] = fmaf(xf[j], wr4[j].x, acc[r][0]);
        acc[r][1] = fmaf(xf[j], wr4[j].y, acc[r][1]);
        acc[r][2] = fmaf(xf[j], wr4[j].z, acc[r][2]);
        acc[r][3] = fmaf(xf[j], wr4[j].w, acc[r][3]);
      }
    }
  }

  const float b0 = bl[c0 + 0], b1 = bl[c0 + 1], b2 = bl[c0 + 2], b3 = bl[c0 + 3];
#pragma unroll
  for (int r = 0; r < R; ++r) {
    const int grow = row0 + rg * R + r;
    if (grow < NN) {
      float o0 = acc[r][0] + b0, o1 = acc[r][1] + b1, o2 = acc[r][2] + b2, o3 = acc[r][3] + b3;
      if (RELU) {
        o0 = fmaxf(o0, 0.f); o1 = fmaxf(o1, 0.f); o2 = fmaxf(o2, 0.f); o3 = fmaxf(o3, 0.f);
      }
      if (DOUT == 64) {
        ushort4 o;
        o.x = f2bf(o0); o.y = f2bf(o1); o.z = f2bf(o2); o.w = f2bf(o3);
        *reinterpret_cast<ushort4*>((u16*)outv + (size_t)grow * 64 + c0) = o;
      } else {
        float4 o = make_float4(o0, o1, o2, o3);
        *reinterpret_cast<float4*>((float*)outv + (size_t)grow * 32 + c0) = o;
      }
    }
  }
}

// ---------------------------------------------------------------------------
extern "C" void kernel_launch(void* const* d_in, const int* in_sizes, int n_in,
                              void* d_out, int out_size, void* d_ws, size_t ws_size,
                              hipStream_t stream) {
  const float* product_x = (const float*)d_in[0];
  const float* user_emb = (const float*)d_in[1];
  const float* brand_emb = (const float*)d_in[2];
  const float* cat_emb = (const float*)d_in[3];
  const float* shop_emb = (const float*)d_in[4];
  const float* proj_W = (const float*)d_in[5];
  const float* proj_b = (const float*)d_in[6];
  const float* c1_Wl = (const float*)d_in[7];
  const float* c1_bl = (const float*)d_in[8];
  const float* c1_Wr = (const float*)d_in[9];
  const float* c2_Wl = (const float*)d_in[10];
  const float* c2_bl = (const float*)d_in[11];
  const float* c2_Wr = (const float*)d_in[12];
  const int* pb_src = (const int*)d_in[13];
  const int* pb_dst = (const int*)d_in[14];
  const int* pc_src = (const int*)d_in[15];
  const int* pc_dst = (const int*)d_in[16];
  const int* ps_src = (const int*)d_in[17];
  const int* ps_dst = (const int*)d_in[18];
  const int* up_src = (const int*)d_in[19];
  const int* up_dst = (const int*)d_in[20];
  const int nPB = in_sizes[13], nPC = in_sizes[15], nPS = in_sizes[17], nUP = in_sizes[19];
  const int nE = nPB + nPC + nPS + nUP;
  const int nDirected = 2 * nE;

  // workspace layout (bf16 tables as u16/u32 views)
  u16* xb = (u16*)d_ws;                          // [NN*64] bf16
  u16* out1 = xb + (size_t)NN * 64;              // [NN*64] bf16
  u16* sbuf = out1 + (size_t)NN * 64;            // [NN*64] bf16 (reused both layers)
  int* eidx = (int*)(sbuf + (size_t)NN * 64);    // [nDirected]
  int* rowptr = eidx + nDirected;                // [NN+1]
  int* cnt = rowptr + (NN + 1);                  // [NN]
  int* cursor = cnt + NN;                        // [NN]
  int* blockSums = cursor + NN;                  // [512]

  hipMemsetAsync(cnt, 0, NN * sizeof(int), stream);
  hipMemsetAsync(cursor, 0, NN * sizeof(int), stream);

  degree_all_kernel<<<(nE + 255) / 256, 256, 0, stream>>>(
      pb_src, pb_dst, pc_src, pc_dst, ps_src, ps_dst, up_src, up_dst, nPB, nPC, nPS, nUP, cnt);

  const int nb = (NN + 1023) / 1024;  // 301
  scan1_kernel<<<nb, 256, 0, stream>>>(cnt, blockSums, NN);
  scan2_kernel<<<1, 512, 0, stream>>>(blockSums, nb);
  scan3_kernel<<<nb, 256, 0, stream>>>(cnt, blockSums, rowptr, NN);

  fill_all_kernel<<<(nE + 255) / 256, 256, 0, stream>>>(
      pb_src, pb_dst, pc_src, pc_dst, ps_src, ps_dst, up_src, up_dst, nPB, nPC, nPS, nUP,
      rowptr, cursor, eidx);

  proj_gemm_kernel<<<(NP + 127) / 128, 256, 0, stream>>>(product_x, proj_W, proj_b, xb);
  cvt_emb_kernel<<<((NU + NBR + NCAT + NSH) * 16 + 255) / 256, 256, 0, stream>>>(
      user_emb, brand_emb, cat_emb, shop_emb, xb);

  // Layer 1
  gather_mean_kernel<<<4096, 256, 0, stream>>>(rowptr, eidx, (const u32*)xb, (u32*)sbuf);
  layer_gemm_kernel<64, true><<<(NN + 127) / 128, 256, 0, stream>>>(
      (const u32*)sbuf, (const u32*)xb, c1_Wl, c1_bl, c1_Wr, out1);
  // Layer 2
  gather_mean_kernel<<<4096, 256, 0, stream>>>(rowptr, eidx, (const u32*)out1, (u32*)sbuf);
  layer_gemm_kernel<32, false><<<(NN + 127) / 128, 256, 0, stream>>>(
      (const u32*)sbuf, (const u32*)out1, c2_Wl, c2_bl, c2_Wr, d_out);
}

// Round 4
// 902.180 us; speedup vs baseline: 2.1747x; 1.1573x over previous
//
#include <hip/hip_runtime.h>

#define NP 200000
#define NU 100000
#define NBR 5000
#define NCAT 2000
#define NSH 1000
#define NN (NP + NU + NBR + NCAT + NSH) /* 308000 */
#define OFF_U NP
#define OFF_B (NP + NU)
#define OFF_C (NP + NU + NBR)
#define OFF_S (NP + NU + NBR + NCAT)

typedef unsigned short u16;
typedef unsigned int u32;
typedef __attribute__((ext_vector_type(8))) short short8;
typedef __attribute__((ext_vector_type(4))) float f32x4;

__device__ __forceinline__ u16 f2bf(float f) {
  union { float f; unsigned u; } v;
  v.f = f;
  unsigned r = (v.u + 0x7fffu + ((v.u >> 16) & 1u)) >> 16;  // RNE
  return (u16)r;
}
__device__ __forceinline__ float uasf(u32 u) {
  union { u32 u; float f; } v;
  v.u = u;
  return v.f;
}
// pack 2 fp32 -> 2 bf16 (RNE) in one instr
__device__ __forceinline__ u32 cvtpk(float lo, float hi) {
  u32 r;
  asm("v_cvt_pk_bf16_f32 %0, %1, %2" : "=v"(r) : "v"(lo), "v"(hi));
  return r;
}

// ---------------------------------------------------------------------------
// MFMA projection: xb[r][c] = bf16(relu(px[r][:] @ W[:][c] + b[c])), r<NP.
// Block: 128 rows x 64 cols, 4 waves; wave owns 16-col tile, W frags in VGPRs.
// A staged fp32->bf16 into XOR-swizzled LDS (double-buffered, 1 barrier/step).
// ---------------------------------------------------------------------------
__global__ __launch_bounds__(256) void proj_mfma_kernel(
    const float* __restrict__ px, const float* __restrict__ W,
    const float* __restrict__ bias, u16* __restrict__ xb) {
  __shared__ u16 lA[2][128 * 32];  // 8 KB per buffer, bf16, swizzled
  const int t = threadIdx.x;
  const int l = t & 63;
  const int wid = t >> 6;
  const int row0 = blockIdx.x * 128;

  // ---- B (W) fragments in registers: cols [wid*16, wid*16+16) ----
  const int n0 = wid * 16 + (l & 15);
  const int kb = (l >> 4) * 8;
  short8 bf[12];
#pragma unroll
  for (int kt = 0; kt < 12; ++kt) {
    union { u32 p[4]; short8 s; } uu;
#pragma unroll
    for (int j = 0; j < 4; ++j) {
      const float lo = W[(size_t)(kt * 32 + kb + 2 * j) * 64 + n0];
      const float hi = W[(size_t)(kt * 32 + kb + 2 * j + 1) * 64 + n0];
      uu.p[j] = cvtpk(lo, hi);
    }
    bf[kt] = uu.s;
  }
  const float bv = bias[n0];

  f32x4 acc[8];
#pragma unroll
  for (int rt = 0; rt < 8; ++rt) {
    f32x4 z = {0.f, 0.f, 0.f, 0.f};
    acc[rt] = z;
  }

  // frag-read base byte addr (within one buffer), swizzle (r&7)<<4 with r&7==l&7
  const int fr_base = (((l & 15) * 64 + (l >> 4) * 16)) ^ ((l & 7) << 4);

  float4 sreg[4];
  // prologue: load k-tile 0 into regs, write buf0
#pragma unroll
  for (int i = 0; i < 4; ++i) {
    const int qi = t + 256 * i;
    const int r = qi >> 3, q = qi & 7;
    const int grow = row0 + r;
    sreg[i] = (grow < NP) ? *reinterpret_cast<const float4*>(px + (size_t)grow * 384 + q * 4)
                          : make_float4(0.f, 0.f, 0.f, 0.f);
  }
#pragma unroll
  for (int i = 0; i < 4; ++i) {
    const int qi = t + 256 * i;
    const int r = qi >> 3, q = qi & 7;
    const int a16 = (((r * 64 + q * 8)) ^ ((r & 7) << 4)) >> 1;  // u16 units
    const u32 p0 = cvtpk(sreg[i].x, sreg[i].y);
    const u32 p1 = cvtpk(sreg[i].z, sreg[i].w);
    *reinterpret_cast<uint2*>(&lA[0][a16]) = make_uint2(p0, p1);
  }

#pragma unroll
  for (int kt = 0; kt < 12; ++kt) {
    const int cur = kt & 1;
    if (kt + 1 < 12) {  // prefetch next A tile into regs
#pragma unroll
      for (int i = 0; i < 4; ++i) {
        const int qi = t + 256 * i;
        const int r = qi >> 3, q = qi & 7;
        const int grow = row0 + r;
        sreg[i] = (grow < NP)
                      ? *reinterpret_cast<const float4*>(px + (size_t)grow * 384 +
                                                         (kt + 1) * 32 + q * 4)
                      : make_float4(0.f, 0.f, 0.f, 0.f);
      }
    }
    __syncthreads();  // buf[cur] writes (prev iter) visible
#pragma unroll
    for (int rt = 0; rt < 8; ++rt) {
      const short8 af =
          *reinterpret_cast<const short8*>(&lA[cur][(fr_base + rt * 1024) >> 1]);
      acc[rt] = __builtin_amdgcn_mfma_f32_16x16x32_bf16(af, bf[kt], acc[rt], 0, 0, 0);
    }
    if (kt + 1 < 12) {  // cvt + write into other buffer (safe: 1 barrier/iter)
#pragma unroll
      for (int i = 0; i < 4; ++i) {
        const int qi = t + 256 * i;
        const int r = qi >> 3, q = qi & 7;
        const int a16 = (((r * 64 + q * 8)) ^ ((r & 7) << 4)) >> 1;
        const u32 p0 = cvtpk(sreg[i].x, sreg[i].y);
        const u32 p1 = cvtpk(sreg[i].z, sreg[i].w);
        *reinterpret_cast<uint2*>(&lA[cur ^ 1][a16]) = make_uint2(p0, p1);
      }
    }
  }

  // epilogue: D[row=(l>>4)*4+r][col=l&15] per m89-verified C/D mapping
#pragma unroll
  for (int rt = 0; rt < 8; ++rt) {
#pragma unroll
    for (int r = 0; r < 4; ++r) {
      const int grow = row0 + rt * 16 + (l >> 4) * 4 + r;
      if (grow < NP)
        xb[(size_t)grow * 64 + n0] = f2bf(fmaxf(acc[rt][r] + bv, 0.f));
    }
  }
}

// ---------------------------------------------------------------------------
// Fused fp32->bf16 conversion of all 4 embedding tables into xb.
// ---------------------------------------------------------------------------
__global__ void cvt_emb_kernel(const float* __restrict__ ue, const float* __restrict__ be,
                               const float* __restrict__ ce, const float* __restrict__ se,
                               u16* __restrict__ xb) {
  const int i = blockIdx.x * 256 + threadIdx.x;  // float4-quad index
  const int totalQ = (NU + NBR + NCAT + NSH) * 16;
  if (i >= totalQ) return;
  const int row = i >> 4, q = i & 15;
  const float* src;
  int lrow;
  if (row < NU) {
    src = ue; lrow = row;
  } else if (row < NU + NBR) {
    src = be; lrow = row - NU;
  } else if (row < NU + NBR + NCAT) {
    src = ce; lrow = row - NU - NBR;
  } else {
    src = se; lrow = row - NU - NBR - NCAT;
  }
  const float4 v = reinterpret_cast<const float4*>(src)[(size_t)lrow * 16 + q];
  ushort4 o;
  o.x = f2bf(v.x);
  o.y = f2bf(v.y);
  o.z = f2bf(v.z);
  o.w = f2bf(v.w);
  reinterpret_cast<ushort4*>(xb + (size_t)(OFF_U + row) * 64)[q] = o;
}

// ---------------------------------------------------------------------------
// CSR build: fused degree count over all 4 relations.
// ---------------------------------------------------------------------------
__global__ void degree_all_kernel(const int* __restrict__ pbs, const int* __restrict__ pbd,
                                  const int* __restrict__ pcs, const int* __restrict__ pcd,
                                  const int* __restrict__ pss, const int* __restrict__ psd,
                                  const int* __restrict__ ups, const int* __restrict__ upd,
                                  int nPB, int nPC, int nPS, int nUP, int* __restrict__ cnt) {
  int e = blockIdx.x * 256 + threadIdx.x;
  int a, b;
  if (e < nPB) {
    a = pbs[e]; b = pbd[e] + OFF_B;
  } else {
    e -= nPB;
    if (e < nPC) {
      a = pcs[e]; b = pcd[e] + OFF_C;
    } else {
      e -= nPC;
      if (e < nPS) {
        a = pss[e]; b = psd[e] + OFF_S;
      } else {
        e -= nPS;
        if (e >= nUP) return;
        a = ups[e] + OFF_U; b = upd[e];
      }
    }
  }
  atomicAdd(&cnt[a], 1);
  atomicAdd(&cnt[b], 1);
}

// 3-kernel exclusive scan cnt[NN] -> rowptr[NN+1]
__global__ __launch_bounds__(256) void scan1_kernel(const int* __restrict__ cnt,
                                                    int* __restrict__ blockSums, int n) {
  __shared__ int sdata[256];
  const int base = blockIdx.x * 1024;
  int s = 0;
  for (int i = threadIdx.x; i < 1024; i += 256) {
    int idx = base + i;
    if (idx < n) s += cnt[idx];
  }
  sdata[threadIdx.x] = s;
  __syncthreads();
  for (int off = 128; off > 0; off >>= 1) {
    if (threadIdx.x < off) sdata[threadIdx.x] += sdata[threadIdx.x + off];
    __syncthreads();
  }
  if (threadIdx.x == 0) blockSums[blockIdx.x] = sdata[0];
}

__global__ __launch_bounds__(512) void scan2_kernel(int* __restrict__ blockSums, int nb) {
  __shared__ int sd[512];
  const int t = threadIdx.x;
  const int v = (t < nb) ? blockSums[t] : 0;
  sd[t] = v;
  __syncthreads();
  for (int off = 1; off < 512; off <<= 1) {
    int add = (t >= off) ? sd[t - off] : 0;
    __syncthreads();
    sd[t] += add;
    __syncthreads();
  }
  if (t < nb) blockSums[t] = sd[t] - v;  // exclusive
}

__global__ __launch_bounds__(256) void scan3_kernel(const int* __restrict__ cnt,
                                                    const int* __restrict__ blockSums,
                                                    int* __restrict__ rowptr, int n) {
  __shared__ int wsum[4];
  const int base = blockIdx.x * 1024;
  const int t = threadIdx.x, lane = t & 63, wid = t >> 6;
  const int idx0 = base + t * 4;
  int v[4];
#pragma unroll
  for (int j = 0; j < 4; ++j) {
    int idx = idx0 + j;
    v[j] = (idx < n) ? cnt[idx] : 0;
  }
  const int s = v[0] + v[1] + v[2] + v[3];
  int incl = s;
  for (int off = 1; off < 64; off <<= 1) {
    int tt = __shfl_up(incl, off);
    if (lane >= off) incl += tt;
  }
  if (lane == 63) wsum[wid] = incl;
  __syncthreads();
  int wOff = 0;
#pragma unroll
  for (int w = 0; w < 4; ++w)
    if (w < wid) wOff += wsum[w];
  int run = blockSums[blockIdx.x] + wOff + (incl - s);
#pragma unroll
  for (int j = 0; j < 4; ++j) {
    int idx = idx0 + j;
    if (idx < n) {
      rowptr[idx] = run;
      run += v[j];
      if (idx == n - 1) rowptr[n] = run;
    }
  }
}

// Fused bucket-scatter of in-neighbor lists over all 4 relations.
__global__ void fill_all_kernel(const int* __restrict__ pbs, const int* __restrict__ pbd,
                                const int* __restrict__ pcs, const int* __restrict__ pcd,
                                const int* __restrict__ pss, const int* __restrict__ psd,
                                const int* __restrict__ ups, const int* __restrict__ upd,
                                int nPB, int nPC, int nPS, int nUP,
                                const int* __restrict__ rowptr, int* __restrict__ cursor,
                                int* __restrict__ eidx) {
  int e = blockIdx.x * 256 + threadIdx.x;
  int a, b;
  if (e < nPB) {
    a = pbs[e]; b = pbd[e] + OFF_B;
  } else {
    e -= nPB;
    if (e < nPC) {
      a = pcs[e]; b = pcd[e] + OFF_C;
    } else {
      e -= nPC;
      if (e < nPS) {
        a = pss[e]; b = psd[e] + OFF_S;
      } else {
        e -= nPS;
        if (e >= nUP) return;
        a = ups[e] + OFF_U; b = upd[e];
      }
    }
  }
  int pa = atomicAdd(&cursor[a], 1);
  eidx[rowptr[a] + pa] = b;
  int pb = atomicAdd(&cursor[b], 1);
  eidx[rowptr[b] + pb] = a;
}

// ---------------------------------------------------------------------------
// Gather-mean: sout[node][:] = bf16(mean_{j in N(node)} xin[j][:]).
// Half-wave per edge; u32 loads (2 bf16 dims); branchless clamp; fp32 accum.
// ---------------------------------------------------------------------------
__global__ __launch_bounds__(256) void gather_mean_kernel(
    const int* __restrict__ rowptr, const int* __restrict__ eidx,
    const u32* __restrict__ xin, u32* __restrict__ sout) {
  const int lane = threadIdx.x & 63;
  const int q = lane & 31;
  const int h = lane >> 5;
  const int wid0 = blockIdx.x * 4 + (threadIdx.x >> 6);
  const int nW = gridDim.x * 4;
  for (int node = wid0; node < NN; node += nW) {
    const int r0 = rowptr[node], r1 = rowptr[node + 1];
    float sl = 0.f, sh = 0.f;
    for (int e = r0; e < r1; e += 8) {
      int nj[4];
#pragma unroll
      for (int j = 0; j < 4; ++j) {
        const int ee = e + 2 * j + h;
        const int ec = (ee < r1 - 1) ? ee : (r1 - 1);
        nj[j] = eidx[ec];
      }
      u32 rv[4];
#pragma unroll
      for (int j = 0; j < 4; ++j) {
        u32 r = xin[(size_t)nj[j] * 32 + q];
        rv[j] = (e + 2 * j + h < r1) ? r : 0u;
      }
#pragma unroll
      for (int j = 0; j < 4; ++j) {
        sl += uasf(rv[j] << 16);
        sh += uasf(rv[j] & 0xffff0000u);
      }
    }
    sl += __shfl_xor(sl, 32);
    sh += __shfl_xor(sh, 32);
    if (h == 0) {
      const int deg = r1 - r0;
      const float inv = (deg > 0) ? (1.f / (float)deg) : 1.f;
      const u32 o = (u32)f2bf(sl * inv) | ((u32)f2bf(sh * inv) << 16);
      sout[(size_t)node * 32 + q] = o;
    }
  }
}

// ---------------------------------------------------------------------------
// Dense layer GEMM: out = act(S @ Wl + bl + X @ Wr), S,X bf16 [NN][64].
// ---------------------------------------------------------------------------
template <int DOUT, bool RELU>
__global__ __launch_bounds__(256) void layer_gemm_kernel(
    const u32* __restrict__ S, const u32* __restrict__ X,
    const float* __restrict__ Wl, const float* __restrict__ bl,
    const float* __restrict__ Wr, void* __restrict__ outv) {
  constexpr int NC = DOUT / 4;   // col groups (16 or 8)
  constexpr int NR = 256 / NC;   // row groups (16 or 32)
  constexpr int R = 128 / NR;    // rows per thread (8 or 4)
  __shared__ __align__(16) u32 lS[128 * 32];
  __shared__ __align__(16) u32 lX[128 * 32];
  __shared__ __align__(16) float lWl[64 * DOUT];
  __shared__ __align__(16) float lWr[64 * DOUT];
  const int t = threadIdx.x;
  const int row0 = blockIdx.x * 128;

#pragma unroll
  for (int i = 0; i < (64 * DOUT) / 1024; ++i) {  // stage W (float4)
    const int idx = i * 256 + t;
    reinterpret_cast<float4*>(lWl)[idx] = reinterpret_cast<const float4*>(Wl)[idx];
    reinterpret_cast<float4*>(lWr)[idx] = reinterpret_cast<const float4*>(Wr)[idx];
  }
#pragma unroll
  for (int i = 0; i < 4; ++i) {  // stage S, X tiles (uint4)
    const int idx = i * 256 + t;
    const int r = idx >> 3, c = idx & 7;
    uint4 vs = make_uint4(0u, 0u, 0u, 0u), vx = vs;
    if (row0 + r < NN) {
      vs = reinterpret_cast<const uint4*>(S)[(size_t)(row0 + r) * 8 + c];
      vx = reinterpret_cast<const uint4*>(X)[(size_t)(row0 + r) * 8 + c];
    }
    reinterpret_cast<uint4*>(lS)[idx] = vs;
    reinterpret_cast<uint4*>(lX)[idx] = vx;
  }
  __syncthreads();

  const int cg = t % NC, rg = t / NC;
  const int c0 = cg * 4;
  float acc[R][4];
#pragma unroll
  for (int r = 0; r < R; ++r)
#pragma unroll
    for (int c = 0; c < 4; ++c) acc[r][c] = 0.f;

  for (int kq = 0; kq < 16; ++kq) {
    float4 wl4[4], wr4[4];
#pragma unroll
    for (int j = 0; j < 4; ++j) {
      wl4[j] = *reinterpret_cast<const float4*>(&lWl[(kq * 4 + j) * DOUT + c0]);
      wr4[j] = *reinterpret_cast<const float4*>(&lWr[(kq * 4 + j) * DOUT + c0]);
    }
#pragma unroll
    for (int r = 0; r < R; ++r) {
      const int row = rg * R + r;
      const uint2 sv = *reinterpret_cast<const uint2*>(&lS[row * 32 + kq * 2]);
      const uint2 xv = *reinterpret_cast<const uint2*>(&lX[row * 32 + kq * 2]);
      const float sf[4] = {uasf(sv.x << 16), uasf(sv.x & 0xffff0000u),
                           uasf(sv.y << 16), uasf(sv.y & 0xffff0000u)};
      const float xf[4] = {uasf(xv.x << 16), uasf(xv.x & 0xffff0000u),
                           uasf(xv.y << 16), uasf(xv.y & 0xffff0000u)};
#pragma unroll
      for (int j = 0; j < 4; ++j) {
        acc[r][0] = fmaf(sf[j], wl4[j].x, acc[r][0]);
        acc[r][1] = fmaf(sf[j], wl4[j].y, acc[r][1]);
        acc[r][2] = fmaf(sf[j], wl4[j].z, acc[r][2]);
        acc[r][3] = fmaf(sf[j], wl4[j].w, acc[r][3]);
        acc[r][0] = fmaf(xf[j], wr4[j].x, acc[r][0]);
        acc[r][1] = fmaf(xf[j], wr4[j].y, acc[r][1]);
        acc[r][2] = fmaf(xf[j], wr4[j].z, acc[r][2]);
        acc[r][3] = fmaf(xf[j], wr4[j].w, acc[r][3]);
      }
    }
  }

  const float b0 = bl[c0 + 0], b1 = bl[c0 + 1], b2 = bl[c0 + 2], b3 = bl[c0 + 3];
#pragma unroll
  for (int r = 0; r < R; ++r) {
    const int grow = row0 + rg * R + r;
    if (grow < NN) {
      float o0 = acc[r][0] + b0, o1 = acc[r][1] + b1, o2 = acc[r][2] + b2, o3 = acc[r][3] + b3;
      if (RELU) {
        o0 = fmaxf(o0, 0.f); o1 = fmaxf(o1, 0.f); o2 = fmaxf(o2, 0.f); o3 = fmaxf(o3, 0.f);
      }
      if (DOUT == 64) {
        ushort4 o;
        o.x = f2bf(o0); o.y = f2bf(o1); o.z = f2bf(o2); o.w = f2bf(o3);
        *reinterpret_cast<ushort4*>((u16*)outv + (size_t)grow * 64 + c0) = o;
      } else {
        float4 o = make_float4(o0, o1, o2, o3);
        *reinterpret_cast<float4*>((float*)outv + (size_t)grow * 32 + c0) = o;
      }
    }
  }
}

// ---------------------------------------------------------------------------
extern "C" void kernel_launch(void* const* d_in, const int* in_sizes, int n_in,
                              void* d_out, int out_size, void* d_ws, size_t ws_size,
                              hipStream_t stream) {
  const float* product_x = (const float*)d_in[0];
  const float* user_emb = (const float*)d_in[1];
  const float* brand_emb = (const float*)d_in[2];
  const float* cat_emb = (const float*)d_in[3];
  const float* shop_emb = (const float*)d_in[4];
  const float* proj_W = (const float*)d_in[5];
  const float* proj_b = (const float*)d_in[6];
  const float* c1_Wl = (const float*)d_in[7];
  const float* c1_bl = (const float*)d_in[8];
  const float* c1_Wr = (const float*)d_in[9];
  const float* c2_Wl = (const float*)d_in[10];
  const float* c2_bl = (const float*)d_in[11];
  const float* c2_Wr = (const float*)d_in[12];
  const int* pb_src = (const int*)d_in[13];
  const int* pb_dst = (const int*)d_in[14];
  const int* pc_src = (const int*)d_in[15];
  const int* pc_dst = (const int*)d_in[16];
  const int* ps_src = (const int*)d_in[17];
  const int* ps_dst = (const int*)d_in[18];
  const int* up_src = (const int*)d_in[19];
  const int* up_dst = (const int*)d_in[20];
  const int nPB = in_sizes[13], nPC = in_sizes[15], nPS = in_sizes[17], nUP = in_sizes[19];
  const int nE = nPB + nPC + nPS + nUP;
  const int nDirected = 2 * nE;

  // workspace layout (bf16 tables as u16/u32 views)
  u16* xb = (u16*)d_ws;                          // [NN*64] bf16
  u16* out1 = xb + (size_t)NN * 64;              // [NN*64] bf16
  u16* sbuf = out1 + (size_t)NN * 64;            // [NN*64] bf16 (reused both layers)
  int* eidx = (int*)(sbuf + (size_t)NN * 64);    // [nDirected]
  int* rowptr = eidx + nDirected;                // [NN+1]
  int* cnt = rowptr + (NN + 1);                  // [NN]
  int* cursor = cnt + NN;                        // [NN]
  int* blockSums = cursor + NN;                  // [512]

  hipMemsetAsync(cnt, 0, NN * sizeof(int), stream);
  hipMemsetAsync(cursor, 0, NN * sizeof(int), stream);

  degree_all_kernel<<<(nE + 255) / 256, 256, 0, stream>>>(
      pb_src, pb_dst, pc_src, pc_dst, ps_src, ps_dst, up_src, up_dst, nPB, nPC, nPS, nUP, cnt);

  const int nb = (NN + 1023) / 1024;  // 301
  scan1_kernel<<<nb, 256, 0, stream>>>(cnt, blockSums, NN);
  scan2_kernel<<<1, 512, 0, stream>>>(blockSums, nb);
  scan3_kernel<<<nb, 256, 0, stream>>>(cnt, blockSums, rowptr, NN);

  fill_all_kernel<<<(nE + 255) / 256, 256, 0, stream>>>(
      pb_src, pb_dst, pc_src, pc_dst, ps_src, ps_dst, up_src, up_dst, nPB, nPC, nPS, nUP,
      rowptr, cursor, eidx);

  proj_mfma_kernel<<<(NP + 127) / 128, 256, 0, stream>>>(product_x, proj_W, proj_b, xb);
  cvt_emb_kernel<<<((NU + NBR + NCAT + NSH) * 16 + 255) / 256, 256, 0, stream>>>(
      user_emb, brand_emb, cat_emb, shop_emb, xb);

  // Layer 1
  gather_mean_kernel<<<4096, 256, 0, stream>>>(rowptr, eidx, (const u32*)xb, (u32*)sbuf);
  layer_gemm_kernel<64, true><<<(NN + 127) / 128, 256, 0, stream>>>(
      (const u32*)sbuf, (const u32*)xb, c1_Wl, c1_bl, c1_Wr, out1);
  // Layer 2
  gather_mean_kernel<<<4096, 256, 0, stream>>>(rowptr, eidx, (const u32*)out1, (u32*)sbuf);
  layer_gemm_kernel<32, false><<<(NN + 127) / 128, 256, 0, stream>>>(
      (const u32*)sbuf, (const u32*)out1, c2_Wl, c2_bl, c2_Wr, d_out);
}